// Round 3
// baseline (1310.469 us; speedup 1.0000x reference)
//
#include <hip/hip_runtime.h>

// SRLSecondOrderScorer: B=2, N=128, D_IN=1024, D=150.
// Inputs float32, outputs float32 (round-2 evidence: stub-identical absmax 454
// with half-written buffer => f32 out; round-1 NaN => f32 in).
// Decomposition per triaffine: wz = Z . T (over k), tmp = X . wz (over i),
// s = tmp . Y^T (over j). Sym epilogue in-place; cop via transpose kernel.

#define BATCH 2
#define NN    128
#define DIN   1024
#define DD    150
#define DPAD  152          // padded row stride (16B-aligned rows: 152*4=608)
#define BN    256          // BATCH*NN
#define OUTBLK 4194304     // 2*128^3
#define HREG  (BN*DPAD)    // floats per MLP output region

// ---------------- MLP: H[m][bn][d] = leaky_relu(x @ W_m + b_m) ----------------
__global__ __launch_bounds__(256) void mlp_kernel(
    const float* __restrict__ x,
    const float* __restrict__ W0, const float* __restrict__ B0,
    const float* __restrict__ W1, const float* __restrict__ B1,
    const float* __restrict__ W2, const float* __restrict__ B2,
    float* __restrict__ H)
{
  int blk = blockIdx.x;              // 0..767
  int m = blk >> 8;
  int bn = blk & 255;
  const float* W  = (m == 0) ? W0 : (m == 1) ? W1 : W2;
  const float* Bv = (m == 0) ? B0 : (m == 1) ? B1 : B2;
  __shared__ float xl[DIN];
  int tid = threadIdx.x;
  for (int i = tid; i < DIN; i += 256) xl[i] = x[bn * DIN + i];
  __syncthreads();
  if (tid < DD) {
    float acc = Bv[tid];
    #pragma unroll 4
    for (int i = 0; i < DIN; ++i) acc += xl[i] * W[i * DD + tid];
    float v = acc > 0.f ? acc : 0.1f * acc;
    H[(m * BN + bn) * DPAD + tid] = v;
  } else if (tid < DPAD) {
    H[(m * BN + bn) * DPAD + tid] = 0.f;   // zero pads (safe for vector loads)
  }
}

// ---------- wz[bz][i][j] = sum_k Z[bz][k] * T[i][k][j] ----------
// grid (150, 8), block 192. A-tile = 32 bz rows of Z in LDS.
__global__ __launch_bounds__(192) void wz_kernel(
    const float* __restrict__ Z,   // H region [BN][DPAD]
    const float* __restrict__ T,   // [150][150][150]
    float* __restrict__ wz)        // [BN][150][150]
{
  int i = blockIdx.x;
  int bz0 = blockIdx.y << 5;
  __shared__ float zl[32][DPAD];
  int tid = threadIdx.x;
  for (int l = tid; l < 32 * DPAD; l += 192) {
    int r = l / DPAD, c = l - r * DPAD;
    zl[r][c] = Z[(bz0 + r) * DPAD + c];  // pads already zero
  }
  __syncthreads();
  int j = tid;
  if (j >= DD) return;
  float acc[32];
  #pragma unroll
  for (int t = 0; t < 32; ++t) acc[t] = 0.f;
  const float* Tr = T + i * DD * DD;
  for (int q = 0; q < 37; ++q) {            // k = 0..147
    int k = q * 4;
    float t0 = Tr[(k + 0) * DD + j];
    float t1 = Tr[(k + 1) * DD + j];
    float t2 = Tr[(k + 2) * DD + j];
    float t3 = Tr[(k + 3) * DD + j];
    #pragma unroll
    for (int t = 0; t < 32; ++t) {
      float4 zq = *(const float4*)&zl[t][k];
      acc[t] += zq.x * t0 + zq.y * t1 + zq.z * t2 + zq.w * t3;
    }
  }
  { // tail k = 148,149 (stay in-bounds of T)
    float t0 = Tr[148 * DD + j];
    float t1 = Tr[149 * DD + j];
    #pragma unroll
    for (int t = 0; t < 32; ++t) acc[t] += zl[t][148] * t0 + zl[t][149] * t1;
  }
  for (int t = 0; t < 32; ++t)
    wz[((bz0 + t) * DD + i) * DD + j] = acc[t];
}

// ---------- tmp[bz][x][j] = sum_i X[b][x][i] * wz[bz][i][j] ----------
// grid (256, 4), block 192. A-tile = 32 x rows of X in LDS.
__global__ __launch_bounds__(192) void tmp_kernel(
    const float* __restrict__ X,    // H region [BN][DPAD]
    const float* __restrict__ wz,   // [BN][150][150]
    float* __restrict__ tmpo)       // [BN][128][DPAD]
{
  int bz = blockIdx.x;
  int x0 = blockIdx.y << 5;
  int b = bz >> 7;
  __shared__ float xl[32][DPAD];
  int tid = threadIdx.x;
  for (int l = tid; l < 32 * DPAD; l += 192) {
    int r = l / DPAD, c = l - r * DPAD;
    xl[r][c] = X[(b * NN + x0 + r) * DPAD + c];
  }
  __syncthreads();
  int j = tid;
  const float* wzb = wz + bz * (DD * DD);
  if (j < DD) {
    float acc[32];
    #pragma unroll
    for (int t = 0; t < 32; ++t) acc[t] = 0.f;
    for (int q = 0; q < 37; ++q) {          // i = 0..147
      int i = q * 4;
      float w0 = wzb[(i + 0) * DD + j];
      float w1 = wzb[(i + 1) * DD + j];
      float w2 = wzb[(i + 2) * DD + j];
      float w3 = wzb[(i + 3) * DD + j];
      #pragma unroll
      for (int t = 0; t < 32; ++t) {
        float4 xq = *(const float4*)&xl[t][i];
        acc[t] += xq.x * w0 + xq.y * w1 + xq.z * w2 + xq.w * w3;
      }
    }
    { // tail i = 148,149
      float w0 = wzb[148 * DD + j];
      float w1 = wzb[149 * DD + j];
      #pragma unroll
      for (int t = 0; t < 32; ++t) acc[t] += xl[t][148] * w0 + xl[t][149] * w1;
    }
    for (int t = 0; t < 32; ++t)
      tmpo[((bz << 7) + x0 + t) * DPAD + j] = acc[t];
  } else if (j < DPAD) {
    for (int t = 0; t < 32; ++t)            // zero pads for s_kernel vector loads
      tmpo[((bz << 7) + x0 + t) * DPAD + j] = 0.f;
  }
}

// ---------- s[bz][x][y] = sum_j tmp[bz][x][j] * Y[b][y][j], f32 out ----------
// grid (256, 4), block 128 (threads = y). A-tile = 32 x rows of tmp in LDS.
__global__ __launch_bounds__(128) void s_kernel(
    const float* __restrict__ tmpo, // [BN][128][DPAD]
    const float* __restrict__ Y,    // H region [BN][DPAD]
    float* __restrict__ sdst)       // [BN][128][128] f32
{
  int bz = blockIdx.x;
  int x0 = blockIdx.y << 5;
  int b = bz >> 7;
  __shared__ float xl[32][DPAD];
  int tid = threadIdx.x;
  for (int l = tid; l < 32 * DPAD; l += 128) {
    int r = l / DPAD, c = l - r * DPAD;
    xl[r][c] = tmpo[((bz << 7) + x0 + r) * DPAD + c];
  }
  __syncthreads();
  int y = tid;
  const float4* yrow = (const float4*)(Y + (b * NN + y) * DPAD);
  float acc[32];
  #pragma unroll
  for (int t = 0; t < 32; ++t) acc[t] = 0.f;
  for (int q = 0; q < DPAD / 4; ++q) {       // 38 quads; pads are zero both sides
    float4 yq = yrow[q];
    #pragma unroll
    for (int t = 0; t < 32; ++t) {
      float4 xq = *(const float4*)&xl[t][q * 4];
      acc[t] += xq.x * yq.x + xq.y * yq.y + xq.z * yq.z + xq.w * yq.w;
    }
  }
  for (int t = 0; t < 32; ++t)
    sdst[((bz << 7) + x0 + t) * NN + y] = acc[t];   // coalesced over y
}

// ---------- in-place triu_sym: s[b,z,x,y] (x>y) = s[b,z,y,x] ----------
__global__ __launch_bounds__(256) void sym_kernel(float* __restrict__ s)
{
  int o = blockIdx.x * 256 + threadIdx.x;   // 0..4194303
  int y = o & 127;
  int x = (o >> 7) & 127;
  if (x > y) {
    int bz = o >> 14;
    s[o] = s[(bz << 14) + (y << 7) + x];    // reads only the (never-written) upper tri
  }
}

// ---------- cop: out[b,x,y,z] = s_plain[b,z,min(x,y),max(x,y)] ----------
// LDS-tiled transpose of (z) x (w=x*128+y). grid (512, 4, 2), block 256.
__global__ __launch_bounds__(256) void cop_kernel(
    const float* __restrict__ ss,  // plain s [BN][128][128] f32
    float* __restrict__ outp)      // [B][128][128][128] f32
{
  int w0 = blockIdx.x << 5;
  int z0 = blockIdx.y << 5;
  int b  = blockIdx.z;
  __shared__ float tl[32][33];
  int tid = threadIdx.x;
  #pragma unroll
  for (int e = 0; e < 4; ++e) {
    int l = e * 256 + tid;
    int r = l >> 5;        // z local
    int c = l & 31;        // w local
    int w = w0 + c;
    int xx = w >> 7, yy = w & 127;
    int sx = xx < yy ? xx : yy;
    int sy = xx < yy ? yy : xx;
    tl[r][c] = ss[(((b << 7) + z0 + r) << 14) + (sx << 7) + sy];
  }
  __syncthreads();
  #pragma unroll
  for (int e = 0; e < 4; ++e) {
    int l = e * 256 + tid;
    int rr = l >> 5;       // w local
    int cc = l & 31;       // z local
    outp[(b << 21) + ((w0 + rr) << 7) + z0 + cc] = tl[cc][rr];
  }
}

extern "C" void kernel_launch(void* const* d_in, const int* in_sizes, int n_in,
                              void* d_out, int out_size, void* d_ws, size_t ws_size,
                              hipStream_t stream)
{
  const float* x   = (const float*)d_in[0];
  const float* Wsh = (const float*)d_in[1];
  const float* bsh = (const float*)d_in[2];
  const float* Wst = (const float*)d_in[3];
  const float* bst = (const float*)d_in[4];
  const float* Wp  = (const float*)d_in[5];
  const float* bp  = (const float*)d_in[6];
  const float* Tpt    = (const float*)d_in[7];
  const float* Tph    = (const float*)d_in[8];
  const float* Tphsib = (const float*)d_in[9];
  const float* Tptsib = (const float*)d_in[10];
  const float* Tphcop = (const float*)d_in[11];
  const float* Tptcop = (const float*)d_in[12];
  float* out = (float*)d_out;
  float* ws = (float*)d_ws;

  float* H   = ws;                    // 3 * 38912 floats (~0.47 MB)
  float* wz  = ws + 3 * HREG;         // 5,760,000 floats (23.0 MB)
  float* tmp = wz + BN * DD * DD;     // 4,980,736 floats (19.9 MB); total ~43.4 MB
  float* ss  = wz;                    // cop scratch (16 MB) aliases wz (dead by then)

  const float* sh = H;
  const float* st = H + HREG;
  const float* pp = H + 2 * HREG;

  mlp_kernel<<<dim3(768), dim3(256), 0, stream>>>(x, Wsh, bsh, Wst, bst, Wp, bp, H);

  struct Cfg {
    const float *X, *Y, *Z, *T;
    float* sdst;
    int mode;                 // 0 = plain, 1 = sym in-place, 2 = cop
    float* outp;
  };
  // outputs in return order: span_psh, span_pst, ph_sib, pt_sib, ph_cop, pt_cop
  Cfg cfgs[6] = {
    { sh, st, pp, Tph,    out + 0 * OUTBLK, 0, nullptr },
    { sh, st, pp, Tpt,    out + 1 * OUTBLK, 1, nullptr },
    { sh, sh, pp, Tphsib, out + 2 * OUTBLK, 1, nullptr },
    { st, st, pp, Tptsib, out + 3 * OUTBLK, 1, nullptr },
    { pp, pp, sh, Tphcop, ss,               2, out + 4 * OUTBLK },
    { pp, pp, st, Tptcop, ss,               2, out + 5 * OUTBLK },
  };

  for (int t = 0; t < 6; ++t) {
    wz_kernel <<<dim3(150, 8), dim3(192), 0, stream>>>(cfgs[t].Z, cfgs[t].T, wz);
    tmp_kernel<<<dim3(256, 4), dim3(192), 0, stream>>>(cfgs[t].X, wz, tmp);
    s_kernel  <<<dim3(256, 4), dim3(128), 0, stream>>>(tmp, cfgs[t].Y, cfgs[t].sdst);
    if (cfgs[t].mode == 1)
      sym_kernel<<<dim3(16384), dim3(256), 0, stream>>>(cfgs[t].sdst);
    else if (cfgs[t].mode == 2)
      cop_kernel<<<dim3(512, 4, 2), dim3(256), 0, stream>>>(ss, cfgs[t].outp);
  }
}

// Round 4
// 551.544 us; speedup vs baseline: 2.3760x; 2.3760x over previous
//
#include <hip/hip_runtime.h>

// SRLSecondOrderScorer: B=2, N=128, D_IN=1024, D=150. Inputs f32, outputs f32.
// Round 4: bf16 MFMA (16x16x32) for all triaffine GEMMs.
// Chain per group: TT3[j*160+i][k] = bf16(T[i][k][j])   (pre-transpose)
//   wz3[bz][j*160+i] = sum_k Z[bz,k]*TT3[(j,i)][k]      (GEMM, A=H-Z, BT=TT3)
//   tmp3[bz][x][j]   = sum_i X[b,x,i]*wz3[bz][j*160+i]  (GEMM, A=H-X, BT=wz3[bz])
//   s[bz][x][y]      = sum_j tmp3[bz][x][j]*Y[b,y,j]    (GEMM, A=tmp3, BT=H-Y)
// H rows padded to 160 with exact zeros => K-padding is inert.

#define NNE   128
#define DD    150
#define KP    160            // padded K / row length (bf16 elements)
#define BN    256
#define OUTBLK 4194304       // 2*128^3 floats
#define NWZ   24064          // wz3 row length (188*128), n>=24000 is pad
#define HROW  (256*160)      // elements per H region

__device__ __forceinline__ unsigned short f2u(float f) {  // RNE f32->bf16
  unsigned x = __float_as_uint(f);
  x += 0x7FFFu + ((x >> 16) & 1u);
  return (unsigned short)(x >> 16);
}

typedef __attribute__((ext_vector_type(8))) short frag8;
typedef __attribute__((ext_vector_type(4))) float facc4;

// ---------------- MLP split-K partials: P[m][ks][bn][160] ----------------
__global__ __launch_bounds__(256) void mlp_partial(
    const float* __restrict__ x,
    const float* __restrict__ W0, const float* __restrict__ W1, const float* __restrict__ W2,
    float* __restrict__ P)
{
  int m = blockIdx.x, bt = blockIdx.y, ks = blockIdx.z;
  const float* W = (m == 0) ? W0 : (m == 1) ? W1 : W2;
  int bn0 = bt * 32, k0 = ks * 128;
  __shared__ float xs[32][132];
  int tid = threadIdx.x;
  for (int e = 0; e < 4; ++e) {
    int l = e * 256 + tid;              // 1024 float4 units = 32 rows x 32
    int row = l >> 5, c4 = l & 31;
    float4 v = *(const float4*)&x[(bn0 + row) * 1024 + k0 + c4 * 4];
    xs[row][c4 * 4 + 0] = v.x; xs[row][c4 * 4 + 1] = v.y;
    xs[row][c4 * 4 + 2] = v.z; xs[row][c4 * 4 + 3] = v.w;
  }
  __syncthreads();
  int tj = tid & 15, tt = tid >> 4, r = tt * 2;
  int dd[10];
  #pragma unroll
  for (int u = 0; u < 10; ++u) { int d = tj + 16 * u; dd[u] = d < 150 ? d : 149; }
  float a0[10], a1[10];
  #pragma unroll
  for (int u = 0; u < 10; ++u) { a0[u] = 0.f; a1[u] = 0.f; }
  for (int k = 0; k < 128; ++k) {
    float xa = xs[r][k], xb = xs[r + 1][k];
    const float* wr = W + (long long)(k0 + k) * 150;
    #pragma unroll
    for (int u = 0; u < 10; ++u) {
      float w = wr[dd[u]];
      a0[u] += xa * w; a1[u] += xb * w;
    }
  }
  float* Pb = P + (long long)(m * 8 + ks) * 256 * 160;
  #pragma unroll
  for (int u = 0; u < 10; ++u) {
    int d = tj + 16 * u;
    Pb[(bn0 + r) * 160 + d]     = a0[u];
    Pb[(bn0 + r + 1) * 160 + d] = a1[u];
  }
}

// ---------------- MLP reduce: H[m][bn][160] bf16 (pads exact zero) ----------------
__global__ __launch_bounds__(256) void mlp_reduce(
    const float* __restrict__ P,
    const float* __restrict__ B0, const float* __restrict__ B1, const float* __restrict__ B2,
    unsigned short* __restrict__ H)
{
  int o = blockIdx.x * 256 + threadIdx.x;     // < 3*256*160
  int d = o % 160;
  int bn = (o / 160) & 255;
  int m = o / (160 * 256);
  float v = 0.f;
  if (d < 150) {
    const float* Bv = (m == 0) ? B0 : (m == 1) ? B1 : B2;
    v = Bv[d];
    #pragma unroll
    for (int ks = 0; ks < 8; ++ks)
      v += P[((long long)(m * 8 + ks) * 256 + bn) * 160 + d];
    v = v > 0.f ? v : 0.1f * v;
  }
  H[o] = f2u(v);
}

// ------------- TT3[(j*160+i)][k] = bf16(T[i][k][j]), k>=150 zero -------------
__global__ __launch_bounds__(256) void tt_kernel(
    const float* __restrict__ T, unsigned short* __restrict__ TT3)
{
  int i = blockIdx.x;                  // 0..149
  int k0 = blockIdx.y * 32, j0 = blockIdx.z * 32;
  __shared__ float tl[32][33];
  int tid = threadIdx.x;
  #pragma unroll
  for (int e = 0; e < 4; ++e) {
    int l = e * 256 + tid;
    int r = l >> 5, c = l & 31;
    float v = 0.f;
    if (k0 + r < 150 && j0 + c < 150) v = T[i * 22500 + (k0 + r) * 150 + (j0 + c)];
    tl[r][c] = v;
  }
  __syncthreads();
  #pragma unroll
  for (int e = 0; e < 4; ++e) {
    int l = e * 256 + tid;
    int rr = l >> 5, cc = l & 31;
    if (j0 + rr < 150)
      TT3[(long long)((j0 + rr) * 160 + i) * 160 + k0 + cc] = f2u(tl[cc][rr]);
  }
}

// ---- zero the i-pad rows (j<150, i in [150,160)) of TT3; must be finite ----
__global__ __launch_bounds__(256) void zpad_kernel(unsigned short* __restrict__ TT3)
{
  int idx = blockIdx.x * 256 + threadIdx.x;   // < 150*10*160 = 240000
  if (idx >= 240000) return;
  int j = idx / 1600;
  int r = idx - j * 1600;
  int i = 150 + r / 160;
  int k = r - (r / 160) * 160;
  TT3[(long long)(j * 160 + i) * 160 + k] = 0;
}

// ---------------- generic bf16 MFMA GEMM: C[128 x NSUB*32] per block ----------------
// C[m][n] = sum_k A[m][k] * BT[n][k], K=160 (chunks 64,64,32), block 256 thr (4 waves),
// wave tile 64m x NSUB*16 n. LDS rows padded to 72 shorts (144B) -> 2-way banks (free).
template<int NSUB, int OBF>
__global__ __launch_bounds__(256) void gemm_kernel(
    const unsigned short* __restrict__ A, long long azs, int azh, int lda,
    const unsigned short* __restrict__ BT, long long bzs, int bzh, int ldb, int nbt,
    void* __restrict__ Cp, long long czs, int ldc)
{
  constexpr int BNT = NSUB * 32;
  constexpr int LR = 72;
  __shared__ unsigned short lA[128 * LR];
  __shared__ unsigned short lB[BNT * LR];
  int z = blockIdx.z, tid = threadIdx.x;
  const unsigned short* Ab = A + (long long)(z >> azh) * azs + (long long)blockIdx.y * 128 * lda;
  const unsigned short* Bb = BT + (long long)(z >> bzh) * bzs;
  int n0 = blockIdx.x * BNT;
  int wave = tid >> 6, lane = tid & 63;
  int l15 = lane & 15, lq = lane >> 4;
  int mw = (wave & 1) * 64, nw = (wave >> 1) * (NSUB * 16);
  facc4 acc[4][NSUB];
  #pragma unroll
  for (int i = 0; i < 4; ++i)
    #pragma unroll
    for (int j = 0; j < NSUB; ++j) acc[i][j] = (facc4){0.f, 0.f, 0.f, 0.f};

  for (int ch = 0; ch < 3; ++ch) {
    int k0 = ch << 6;
    int sh = (ch == 2) ? 2 : 3;          // 16B units per row this chunk
    int upr = 1 << sh;
    for (int u = tid; u < 128 * upr; u += 256) {
      int row = u >> sh, off = (u & (upr - 1)) << 3;
      *(uint4*)&lA[row * LR + off] = *(const uint4*)&Ab[(long long)row * lda + k0 + off];
    }
    for (int u = tid; u < BNT * upr; u += 256) {
      int row = u >> sh, off = (u & (upr - 1)) << 3;
      int gn = n0 + row;
      uint4 v; v.x = 0u; v.y = 0u; v.z = 0u; v.w = 0u;
      if (gn < nbt) v = *(const uint4*)&Bb[(long long)gn * ldb + k0 + off];
      *(uint4*)&lB[row * LR + off] = v;
    }
    __syncthreads();
    int nks = (ch == 2) ? 1 : 2;
    for (int ks = 0; ks < nks; ++ks) {
      int ko = (ks << 5) + (lq << 3);
      frag8 af[4], bf[NSUB];
      #pragma unroll
      for (int i = 0; i < 4; ++i)
        af[i] = *(const frag8*)&lA[(mw + i * 16 + l15) * LR + ko];
      #pragma unroll
      for (int j = 0; j < NSUB; ++j)
        bf[j] = *(const frag8*)&lB[(nw + j * 16 + l15) * LR + ko];
      #pragma unroll
      for (int i = 0; i < 4; ++i)
        #pragma unroll
        for (int j = 0; j < NSUB; ++j)
          acc[i][j] = __builtin_amdgcn_mfma_f32_16x16x32_bf16(af[i], bf[j], acc[i][j], 0, 0, 0);
    }
    __syncthreads();
  }
  long long cb = (long long)z * czs;
  int mb = blockIdx.y * 128 + mw;
  #pragma unroll
  for (int i = 0; i < 4; ++i) {
    #pragma unroll
    for (int r = 0; r < 4; ++r) {
      int m = mb + i * 16 + lq * 4 + r;
      long long rowb = cb + (long long)m * ldc;
      #pragma unroll
      for (int j = 0; j < NSUB; ++j) {
        int col = n0 + nw + j * 16 + l15;
        float v = acc[i][j][r];
        if (OBF) ((unsigned short*)Cp)[rowb + col] = f2u(v);
        else     ((float*)Cp)[rowb + col] = v;
      }
    }
  }
}

// ---------- in-place triu_sym: s[b,z,x,y] (x>y) = s[b,z,y,x] (f32) ----------
__global__ __launch_bounds__(256) void sym_kernel(float* __restrict__ s)
{
  int o = blockIdx.x * 256 + threadIdx.x;
  int y = o & 127;
  int x = (o >> 7) & 127;
  if (x > y) {
    int bz = o >> 14;
    s[o] = s[(bz << 14) + (y << 7) + x];
  }
}

// ---------- cop: out[b,x,y,z] = s_plain[b,z,min(x,y),max(x,y)] (f32) ----------
__global__ __launch_bounds__(256) void cop_kernel(
    const float* __restrict__ ss, float* __restrict__ outp)
{
  int w0 = blockIdx.x << 5;
  int z0 = blockIdx.y << 5;
  int b  = blockIdx.z;
  __shared__ float tl[32][33];
  int tid = threadIdx.x;
  #pragma unroll
  for (int e = 0; e < 4; ++e) {
    int l = e * 256 + tid;
    int r = l >> 5, c = l & 31;
    int w = w0 + c;
    int xx = w >> 7, yy = w & 127;
    int sx = xx < yy ? xx : yy;
    int sy = xx < yy ? yy : xx;
    tl[r][c] = ss[(((b << 7) + z0 + r) << 14) + (sx << 7) + sy];
  }
  __syncthreads();
  #pragma unroll
  for (int e = 0; e < 4; ++e) {
    int l = e * 256 + tid;
    int rr = l >> 5, cc = l & 31;
    outp[(b << 21) + ((w0 + rr) << 7) + z0 + cc] = tl[cc][rr];
  }
}

extern "C" void kernel_launch(void* const* d_in, const int* in_sizes, int n_in,
                              void* d_out, int out_size, void* d_ws, size_t ws_size,
                              hipStream_t stream)
{
  const float* x   = (const float*)d_in[0];
  const float* Wsh = (const float*)d_in[1];
  const float* bsh = (const float*)d_in[2];
  const float* Wst = (const float*)d_in[3];
  const float* bst = (const float*)d_in[4];
  const float* Wp  = (const float*)d_in[5];
  const float* bp  = (const float*)d_in[6];
  const float* Tlist[6] = {
    (const float*)d_in[8],   // T_ph    (span_psh)
    (const float*)d_in[7],   // T_pt    (span_pst)
    (const float*)d_in[9],   // T_phsib
    (const float*)d_in[10],  // T_ptsib
    (const float*)d_in[11],  // T_phcop
    (const float*)d_in[12],  // T_ptcop
  };
  float* out = (float*)d_out;
  char* wsb = (char*)d_ws;

  // ws layout (bytes): H 245760 | TT3 7,680,000 | wz3 12,320,768 | tmp3 10,485,760
  // P (3.93MB) aliases wz3 (dead before first wz write); ss (16.78MB) aliases TT3+wz3.
  unsigned short* Hb   = (unsigned short*)(wsb);
  unsigned short* TT3  = (unsigned short*)(wsb + 245760);
  unsigned short* wz3  = (unsigned short*)(wsb + 7925760);
  unsigned short* tmp3 = (unsigned short*)(wsb + 20246528);
  float* P  = (float*)wz3;        // MLP partials (used before wz3 exists)
  float* ss = (float*)TT3;        // cop scratch  (used after TT3/wz3 dead in-group)

  const unsigned short* sh = Hb;
  const unsigned short* st = Hb + HROW;
  const unsigned short* pp = Hb + 2 * HROW;

  mlp_partial<<<dim3(3, 8, 8), 256, 0, stream>>>(x, Wsh, Wst, Wp, P);
  mlp_reduce <<<dim3(480),     256, 0, stream>>>(P, bsh, bst, bp, Hb);

  struct Cfg {
    const unsigned short *Z, *X, *Y;
    float* sdst;
    int mode;                 // 0 = plain, 1 = sym in-place, 2 = cop
    float* outp;
  };
  // outputs in return order: span_psh, span_pst, ph_sib, pt_sib, ph_cop, pt_cop
  Cfg cfgs[6] = {
    { pp, sh, st, out + 0 * OUTBLK, 0, nullptr },
    { pp, sh, st, out + 1 * OUTBLK, 1, nullptr },
    { pp, sh, sh, out + 2 * OUTBLK, 1, nullptr },
    { pp, st, st, out + 3 * OUTBLK, 1, nullptr },
    { sh, pp, pp, ss,               2, out + 4 * OUTBLK },
    { st, pp, pp, ss,               2, out + 5 * OUTBLK },
  };

  for (int t = 0; t < 6; ++t) {
    tt_kernel  <<<dim3(150, 5, 5), 256, 0, stream>>>(Tlist[t], TT3);
    zpad_kernel<<<dim3(938),       256, 0, stream>>>(TT3);
    // wz3[bz][j*160+i] = sum_k Z[bz,k] * TT3[(j,i)][k]
    gemm_kernel<4, 1><<<dim3(188, 2, 1), 256, 0, stream>>>(
        cfgs[t].Z, 0LL, 0, 160,
        TT3, 0LL, 0, 160, 24000,
        (void*)wz3, 0LL, NWZ);
    // tmp3[bz][x][j] = sum_i X[b,x,i] * wz3[bz][j*160+i]
    gemm_kernel<5, 1><<<dim3(1, 1, 256), 256, 0, stream>>>(
        cfgs[t].X, (long long)(128 * 160), 7, 160,
        wz3, (long long)NWZ, 0, 160, 150,
        (void*)tmp3, (long long)(128 * 160), 160);
    // s[bz][x][y] = sum_j tmp3[bz][x][j] * Y[b,y,j]
    gemm_kernel<4, 0><<<dim3(1, 1, 256), 256, 0, stream>>>(
        tmp3, (long long)(128 * 160), 0, 160,
        cfgs[t].Y, (long long)(128 * 160), 7, 160, 128,
        (void*)cfgs[t].sdst, 16384LL, 128);
    if (cfgs[t].mode == 1)
      sym_kernel<<<dim3(16384), 256, 0, stream>>>(cfgs[t].sdst);
    else if (cfgs[t].mode == 2)
      cop_kernel<<<dim3(512, 4, 2), 256, 0, stream>>>(ss, cfgs[t].outp);
  }
}

// Round 5
// 410.906 us; speedup vs baseline: 3.1892x; 1.3423x over previous
//
#include <hip/hip_runtime.h>

// SRLSecondOrderScorer: B=2, N=128, D_IN=1024, D=150. Inputs f32, outputs f32.
// Round 5: batch all 6 triaffine groups per stage (8 launches total).
// Chain per group g: TT3g[g][(j*160+i)][k] = bf16(T_g[i][k][j])
//   wz3g[g][bz][j*160+i] = sum_k Z[bz,k]*TT3                     (MFMA GEMM)
//   tmp3g[g][bz][x][j]   = sum_i X[b,x,i]*wz3                    (MFMA GEMM)
//   s[g][bz][x][y]       = sum_j tmp3*Y[b,y,j]                   (MFMA GEMM)
// H rows padded to 160 with exact zeros => all K-padding inert.

#define DD    150
#define KP    160
#define OUTBLK 4194304       // 2*128^3 floats
#define NWZ   24064          // wz3 row stride (188*128); cols>=24000 written zero
#define TTG   3840000        // shorts per TT3 group (24000 rows x 160)
#define WZG   (256*NWZ)      // shorts per wz3 group
#define HROW  (256*160)      // shorts per H region

__device__ __forceinline__ unsigned short f2u(float f) {  // RNE f32->bf16
  unsigned x = __float_as_uint(f);
  x += 0x7FFFu + ((x >> 16) & 1u);
  return (unsigned short)(x >> 16);
}

typedef __attribute__((ext_vector_type(8))) short frag8;
typedef __attribute__((ext_vector_type(4))) float facc4;

__constant__ int c_zsel[6] = {2, 2, 2, 2, 0, 1};  // Z region per group (sh,st,pp = 0,1,2)
__constant__ int c_xsel[6] = {0, 0, 0, 1, 2, 2};
__constant__ int c_ysel[6] = {1, 1, 0, 1, 2, 2};

// ---------------- MLP split-K partials: P[m][ks][bn][160] ----------------
__global__ __launch_bounds__(256) void mlp_partial(
    const float* __restrict__ x,
    const float* __restrict__ W0, const float* __restrict__ W1, const float* __restrict__ W2,
    float* __restrict__ P)
{
  int m = blockIdx.x, bt = blockIdx.y, ks = blockIdx.z;
  const float* W = (m == 0) ? W0 : (m == 1) ? W1 : W2;
  int bn0 = bt * 32, k0 = ks * 128;
  __shared__ float xs[32][132];
  int tid = threadIdx.x;
  for (int e = 0; e < 4; ++e) {
    int l = e * 256 + tid;
    int row = l >> 5, c4 = l & 31;
    float4 v = *(const float4*)&x[(bn0 + row) * 1024 + k0 + c4 * 4];
    xs[row][c4 * 4 + 0] = v.x; xs[row][c4 * 4 + 1] = v.y;
    xs[row][c4 * 4 + 2] = v.z; xs[row][c4 * 4 + 3] = v.w;
  }
  __syncthreads();
  int tj = tid & 15, tt = tid >> 4, r = tt * 2;
  int dd[10];
  #pragma unroll
  for (int u = 0; u < 10; ++u) { int d = tj + 16 * u; dd[u] = d < 150 ? d : 149; }
  float a0[10], a1[10];
  #pragma unroll
  for (int u = 0; u < 10; ++u) { a0[u] = 0.f; a1[u] = 0.f; }
  for (int k = 0; k < 128; ++k) {
    float xa = xs[r][k], xb = xs[r + 1][k];
    const float* wr = W + (long long)(k0 + k) * 150;
    #pragma unroll
    for (int u = 0; u < 10; ++u) {
      float w = wr[dd[u]];
      a0[u] += xa * w; a1[u] += xb * w;
    }
  }
  float* Pb = P + (long long)(m * 8 + ks) * 256 * 160;
  #pragma unroll
  for (int u = 0; u < 10; ++u) {
    int d = tj + 16 * u;
    Pb[(bn0 + r) * 160 + d]     = a0[u];
    Pb[(bn0 + r + 1) * 160 + d] = a1[u];
  }
}

// ---------------- MLP reduce: H[m][bn][160] bf16 (pads exact zero) ----------------
__global__ __launch_bounds__(256) void mlp_reduce(
    const float* __restrict__ P,
    const float* __restrict__ B0, const float* __restrict__ B1, const float* __restrict__ B2,
    unsigned short* __restrict__ H)
{
  int o = blockIdx.x * 256 + threadIdx.x;     // < 3*256*160
  int d = o % 160;
  int bn = (o / 160) & 255;
  int m = o / (160 * 256);
  float v = 0.f;
  if (d < 150) {
    const float* Bv = (m == 0) ? B0 : (m == 1) ? B1 : B2;
    v = Bv[d];
    #pragma unroll
    for (int ks = 0; ks < 8; ++ks)
      v += P[((long long)(m * 8 + ks) * 256 + bn) * 160 + d];
    v = v > 0.f ? v : 0.1f * v;
  }
  H[o] = f2u(v);
}

// ------ TT3g[g][(j*160+i)][k] = bf16(T_g[i][k][j]); i,k pads zero; all 6 groups ------
struct TPtrs { const float* t[6]; };
__global__ __launch_bounds__(256) void tt_kernel(TPtrs tp, unsigned short* __restrict__ TT3)
{
  int i = blockIdx.x;                  // 0..159
  int ky = blockIdx.y % 5, jy = blockIdx.y / 5;
  int k0 = ky * 32, j0 = jy * 32;
  int g = blockIdx.z;
  const float* T = tp.t[g];
  unsigned short* TT = TT3 + (long long)g * TTG;
  __shared__ float tl[32][33];
  int tid = threadIdx.x;
  #pragma unroll
  for (int e = 0; e < 4; ++e) {
    int l = e * 256 + tid;
    int r = l >> 5, c = l & 31;
    float v = 0.f;
    if (i < 150 && k0 + r < 150 && j0 + c < 150)
      v = T[i * 22500 + (k0 + r) * 150 + (j0 + c)];
    tl[r][c] = v;
  }
  __syncthreads();
  #pragma unroll
  for (int e = 0; e < 4; ++e) {
    int l = e * 256 + tid;
    int rr = l >> 5, cc = l & 31;
    if (j0 + rr < 150)
      TT[(long long)((j0 + rr) * 160 + i) * 160 + k0 + cc] = f2u(tl[cc][rr]);
  }
}

// ---- wz3g[g][m][n] = sum_k Z_g[m,k]*TT3g[g][n][k]; grid (188, 2, 6), bf16 out ----
__global__ __launch_bounds__(256) void wz_gemm(
    const unsigned short* __restrict__ Hb, const unsigned short* __restrict__ TT3,
    unsigned short* __restrict__ wz3)
{
  constexpr int LR = 72;
  __shared__ unsigned short lA[128 * LR];
  __shared__ unsigned short lB[128 * LR];
  int g = blockIdx.z, tid = threadIdx.x;
  const unsigned short* Ab = Hb + c_zsel[g] * HROW + blockIdx.y * 128 * 160;
  const unsigned short* Bb = TT3 + (long long)g * TTG;
  int n0 = blockIdx.x * 128;
  int wave = tid >> 6, lane = tid & 63;
  int l15 = lane & 15, lq = lane >> 4;
  int mw = (wave & 1) * 64, nw = (wave >> 1) * 64;
  facc4 acc[4][4];
  #pragma unroll
  for (int i = 0; i < 4; ++i)
    #pragma unroll
    for (int j = 0; j < 4; ++j) acc[i][j] = (facc4){0.f, 0.f, 0.f, 0.f};
  for (int ch = 0; ch < 3; ++ch) {
    int k0 = ch << 6;
    int sh = (ch == 2) ? 2 : 3, upr = 1 << sh;
    for (int u = tid; u < 128 * upr; u += 256) {
      int row = u >> sh, off = (u & (upr - 1)) << 3;
      *(uint4*)&lA[row * LR + off] = *(const uint4*)&Ab[row * 160 + k0 + off];
    }
    for (int u = tid; u < 128 * upr; u += 256) {
      int row = u >> sh, off = (u & (upr - 1)) << 3;
      int gn = n0 + row;
      uint4 v; v.x = 0u; v.y = 0u; v.z = 0u; v.w = 0u;
      if (gn < 24000) v = *(const uint4*)&Bb[(long long)gn * 160 + k0 + off];
      *(uint4*)&lB[row * LR + off] = v;
    }
    __syncthreads();
    int nks = (ch == 2) ? 1 : 2;
    for (int ks = 0; ks < nks; ++ks) {
      int ko = (ks << 5) + (lq << 3);
      frag8 af[4], bf[4];
      #pragma unroll
      for (int i = 0; i < 4; ++i) af[i] = *(const frag8*)&lA[(mw + i * 16 + l15) * LR + ko];
      #pragma unroll
      for (int j = 0; j < 4; ++j) bf[j] = *(const frag8*)&lB[(nw + j * 16 + l15) * LR + ko];
      #pragma unroll
      for (int i = 0; i < 4; ++i)
        #pragma unroll
        for (int j = 0; j < 4; ++j)
          acc[i][j] = __builtin_amdgcn_mfma_f32_16x16x32_bf16(af[i], bf[j], acc[i][j], 0, 0, 0);
    }
    __syncthreads();
  }
  unsigned short* C = wz3 + (long long)g * WZG;
  int mb = blockIdx.y * 128 + mw;
  #pragma unroll
  for (int i = 0; i < 4; ++i)
    #pragma unroll
    for (int r = 0; r < 4; ++r) {
      int m = mb + i * 16 + lq * 4 + r;
      #pragma unroll
      for (int j = 0; j < 4; ++j)
        C[(long long)m * NWZ + n0 + nw + j * 16 + l15] = f2u(acc[i][j][r]);
    }
}

// ---- tmp3g[z][x][j] = sum_i X[b,x,i]*wz3g[g][bz][j*160+i]; grid (1536), bf16 out ----
__global__ __launch_bounds__(256) void tmp_gemm(
    const unsigned short* __restrict__ Hb, const unsigned short* __restrict__ wz3,
    unsigned short* __restrict__ tmp3)
{
  constexpr int LR = 72;
  __shared__ unsigned short lA[128 * LR];
  __shared__ unsigned short lB[160 * LR];
  int z = blockIdx.x, tid = threadIdx.x;
  int g = z >> 8, bz = z & 255, b = bz >> 7;
  const unsigned short* Ab = Hb + c_xsel[g] * HROW + b * 128 * 160;
  const unsigned short* Bb = wz3 + (long long)g * WZG + (long long)bz * NWZ;
  int wave = tid >> 6, lane = tid & 63;
  int l15 = lane & 15, lq = lane >> 4;
  int mw = (wave & 1) * 64, nw = (wave >> 1) * 80;
  facc4 acc[4][5];
  #pragma unroll
  for (int i = 0; i < 4; ++i)
    #pragma unroll
    for (int j = 0; j < 5; ++j) acc[i][j] = (facc4){0.f, 0.f, 0.f, 0.f};
  for (int ch = 0; ch < 3; ++ch) {
    int k0 = ch << 6;
    int sh = (ch == 2) ? 2 : 3, upr = 1 << sh;
    for (int u = tid; u < 128 * upr; u += 256) {
      int row = u >> sh, off = (u & (upr - 1)) << 3;
      *(uint4*)&lA[row * LR + off] = *(const uint4*)&Ab[row * 160 + k0 + off];
    }
    for (int u = tid; u < 160 * upr; u += 256) {
      int row = u >> sh, off = (u & (upr - 1)) << 3;
      uint4 v; v.x = 0u; v.y = 0u; v.z = 0u; v.w = 0u;
      if (row < 150) v = *(const uint4*)&Bb[row * 160 + k0 + off];
      *(uint4*)&lB[row * LR + off] = v;
    }
    __syncthreads();
    int nks = (ch == 2) ? 1 : 2;
    for (int ks = 0; ks < nks; ++ks) {
      int ko = (ks << 5) + (lq << 3);
      frag8 af[4], bf[5];
      #pragma unroll
      for (int i = 0; i < 4; ++i) af[i] = *(const frag8*)&lA[(mw + i * 16 + l15) * LR + ko];
      #pragma unroll
      for (int j = 0; j < 5; ++j) bf[j] = *(const frag8*)&lB[(nw + j * 16 + l15) * LR + ko];
      #pragma unroll
      for (int i = 0; i < 4; ++i)
        #pragma unroll
        for (int j = 0; j < 5; ++j)
          acc[i][j] = __builtin_amdgcn_mfma_f32_16x16x32_bf16(af[i], bf[j], acc[i][j], 0, 0, 0);
    }
    __syncthreads();
  }
  unsigned short* C = tmp3 + (long long)z * (128 * 160);
  #pragma unroll
  for (int i = 0; i < 4; ++i)
    #pragma unroll
    for (int r = 0; r < 4; ++r) {
      int m = mw + i * 16 + lq * 4 + r;
      #pragma unroll
      for (int j = 0; j < 5; ++j)
        C[m * 160 + nw + j * 16 + l15] = f2u(acc[i][j][r]);
    }
}

// ---- s[z][x][y] = sum_j tmp3g[z][x][j]*Y[b,y,j]; grid (1536), f32 out ----
struct SPtrs { float* p[6]; };
__global__ __launch_bounds__(256) void s_gemm(
    const unsigned short* __restrict__ tmp3, const unsigned short* __restrict__ Hb,
    SPtrs sp)
{
  constexpr int LR = 72;
  __shared__ unsigned short lA[128 * LR];
  __shared__ unsigned short lB[128 * LR];
  int z = blockIdx.x, tid = threadIdx.x;
  int g = z >> 8, bz = z & 255, b = bz >> 7;
  const unsigned short* Ab = tmp3 + (long long)z * (128 * 160);
  const unsigned short* Bb = Hb + c_ysel[g] * HROW + b * 128 * 160;
  int wave = tid >> 6, lane = tid & 63;
  int l15 = lane & 15, lq = lane >> 4;
  int mw = (wave & 1) * 64, nw = (wave >> 1) * 64;
  facc4 acc[4][4];
  #pragma unroll
  for (int i = 0; i < 4; ++i)
    #pragma unroll
    for (int j = 0; j < 4; ++j) acc[i][j] = (facc4){0.f, 0.f, 0.f, 0.f};
  for (int ch = 0; ch < 3; ++ch) {
    int k0 = ch << 6;
    int sh = (ch == 2) ? 2 : 3, upr = 1 << sh;
    for (int u = tid; u < 128 * upr; u += 256) {
      int row = u >> sh, off = (u & (upr - 1)) << 3;
      *(uint4*)&lA[row * LR + off] = *(const uint4*)&Ab[row * 160 + k0 + off];
      *(uint4*)&lB[row * LR + off] = *(const uint4*)&Bb[row * 160 + k0 + off];
    }
    __syncthreads();
    int nks = (ch == 2) ? 1 : 2;
    for (int ks = 0; ks < nks; ++ks) {
      int ko = (ks << 5) + (lq << 3);
      frag8 af[4], bf[4];
      #pragma unroll
      for (int i = 0; i < 4; ++i) af[i] = *(const frag8*)&lA[(mw + i * 16 + l15) * LR + ko];
      #pragma unroll
      for (int j = 0; j < 4; ++j) bf[j] = *(const frag8*)&lB[(nw + j * 16 + l15) * LR + ko];
      #pragma unroll
      for (int i = 0; i < 4; ++i)
        #pragma unroll
        for (int j = 0; j < 4; ++j)
          acc[i][j] = __builtin_amdgcn_mfma_f32_16x16x32_bf16(af[i], bf[j], acc[i][j], 0, 0, 0);
    }
    __syncthreads();
  }
  float* C = sp.p[g] + (long long)bz * 16384;
  #pragma unroll
  for (int i = 0; i < 4; ++i)
    #pragma unroll
    for (int r = 0; r < 4; ++r) {
      int m = mw + i * 16 + lq * 4 + r;
      #pragma unroll
      for (int j = 0; j < 4; ++j)
        C[m * 128 + nw + j * 16 + l15] = acc[i][j][r];
    }
}

// ---------- in-place triu_sym for out blocks 1..3; grid (49152) ----------
__global__ __launch_bounds__(256) void sym_kernel(float* __restrict__ out)
{
  int idx = blockIdx.x * 256 + threadIdx.x;
  int grp = idx >> 22;                 // 0..2 -> out block 1..3
  int o = idx & (OUTBLK - 1);
  float* s = out + (long long)(1 + grp) * OUTBLK;
  int y = o & 127;
  int x = (o >> 7) & 127;
  if (x > y) {
    int bz = o >> 14;
    s[o] = s[(bz << 14) + (y << 7) + x];
  }
}

// ---------- cop: out[b,x,y,z] = ss[g][b,z,min(x,y),max(x,y)]; grid (512,4,4) ----------
__global__ __launch_bounds__(256) void cop_kernel(
    const float* __restrict__ ss, float* __restrict__ out)
{
  int w0 = blockIdx.x << 5;
  int z0 = blockIdx.y << 5;
  int g  = blockIdx.z >> 1, b = blockIdx.z & 1;
  const float* sg = ss + (long long)g * OUTBLK;
  float* outp = out + (long long)(4 + g) * OUTBLK;
  __shared__ float tl[32][33];
  int tid = threadIdx.x;
  #pragma unroll
  for (int e = 0; e < 4; ++e) {
    int l = e * 256 + tid;
    int r = l >> 5, c = l & 31;
    int w = w0 + c;
    int xx = w >> 7, yy = w & 127;
    int sx = xx < yy ? xx : yy;
    int sy = xx < yy ? yy : xx;
    tl[r][c] = sg[(((b << 7) + z0 + r) << 14) + (sx << 7) + sy];
  }
  __syncthreads();
  #pragma unroll
  for (int e = 0; e < 4; ++e) {
    int l = e * 256 + tid;
    int rr = l >> 5, cc = l & 31;
    outp[(b << 21) + ((w0 + rr) << 7) + z0 + cc] = tl[cc][rr];
  }
}

extern "C" void kernel_launch(void* const* d_in, const int* in_sizes, int n_in,
                              void* d_out, int out_size, void* d_ws, size_t ws_size,
                              hipStream_t stream)
{
  const float* x   = (const float*)d_in[0];
  const float* Wsh = (const float*)d_in[1];
  const float* bsh = (const float*)d_in[2];
  const float* Wst = (const float*)d_in[3];
  const float* bst = (const float*)d_in[4];
  const float* Wp  = (const float*)d_in[5];
  const float* bp  = (const float*)d_in[6];
  TPtrs tp;
  tp.t[0] = (const float*)d_in[8];   // T_ph    (span_psh)
  tp.t[1] = (const float*)d_in[7];   // T_pt    (span_pst)
  tp.t[2] = (const float*)d_in[9];   // T_phsib
  tp.t[3] = (const float*)d_in[10];  // T_ptsib
  tp.t[4] = (const float*)d_in[11];  // T_phcop
  tp.t[5] = (const float*)d_in[12];  // T_ptcop
  float* out = (float*)d_out;
  char* wsb = (char*)d_ws;

  // ws layout (bytes): H 245,760 | TT3g 46,080,000 | wz3g 73,924,608 | tmp3g 62,914,560
  // total ~183.2 MB. P (7.9MB) aliases wz3g (dead before wz writes); ss (33.6MB)
  // aliases TT3g (TT3 fully consumed by wz_gemm before s_gemm writes ss).
  unsigned short* Hb   = (unsigned short*)(wsb);
  unsigned short* TT3  = (unsigned short*)(wsb + 245760);
  unsigned short* wz3  = (unsigned short*)(wsb + 46325760);
  unsigned short* tmp3 = (unsigned short*)(wsb + 120250368);
  float* P  = (float*)wz3;
  float* ss = (float*)TT3;

  SPtrs sp;
  sp.p[0] = out + 0LL * OUTBLK;
  sp.p[1] = out + 1LL * OUTBLK;
  sp.p[2] = out + 2LL * OUTBLK;
  sp.p[3] = out + 3LL * OUTBLK;
  sp.p[4] = ss;
  sp.p[5] = ss + OUTBLK;

  mlp_partial<<<dim3(3, 8, 8),   256, 0, stream>>>(x, Wsh, Wst, Wp, P);
  mlp_reduce <<<dim3(480),       256, 0, stream>>>(P, bsh, bst, bp, Hb);
  tt_kernel  <<<dim3(160, 25, 6),256, 0, stream>>>(tp, TT3);
  wz_gemm    <<<dim3(188, 2, 6), 256, 0, stream>>>(Hb, TT3, wz3);
  tmp_gemm   <<<dim3(1536),      256, 0, stream>>>(Hb, wz3, tmp3);
  s_gemm     <<<dim3(1536),      256, 0, stream>>>(tmp3, Hb, sp);
  sym_kernel <<<dim3(49152),     256, 0, stream>>>(out);
  cop_kernel <<<dim3(512, 4, 4), 256, 0, stream>>>(ss, out);
}